// Round 1
// 326.545 us; speedup vs baseline: 1.0184x; 1.0184x over previous
//
#include <hip/hip_runtime.h>

// Problem constants (match reference)
#define NN 100000
#define TT 128
#define EE 1600000
#define KK 9
#define NSPLIT 16                 // n-splits for output matmul

// Binned CSR build: 512-node buckets
#define BSH 9
#define BMASK 511
#define NBUCK 196                 // ceil(100000/512)
#define BCAP 10240                // avg 8163/bucket, sigma~90 -> 23 sigma headroom
#define EPB 4096                  // edges per bin block
#define BINB 391                  // ceil(EE/EPB)
#define CVTB 3125                 // NN*TT/4 / 1024

typedef _Float16 f16;
typedef __attribute__((ext_vector_type(2))) _Float16 f16x2;
typedef __attribute__((ext_vector_type(4))) _Float16 f16x4;
typedef __attribute__((ext_vector_type(8))) _Float16 f16x8;

union HU8 { f16x8 h; int4 i; };

// ---------- fused: bin edges (blocks 0..BINB) + x fp32->fp16 + zero out ----------
// Packed edge: (dlocal << 20) | src   (src < 2^17, dlocal < 2^9)
__global__ __launch_bounds__(1024)
void bin_cvt_kernel(const int* __restrict__ ei, int* __restrict__ gcursor,
                    unsigned int* __restrict__ binned,
                    const float4* __restrict__ x, f16x4* __restrict__ x16,
                    float* __restrict__ out) {
    __shared__ int hist[NBUCK];
    __shared__ int gbase[NBUCK];
    int tid = threadIdx.x;

    if (blockIdx.x >= BINB + CVTB) {          // one block: zero the output accumulator
        if (tid < TT * 3) out[tid] = 0.0f;
        return;
    }
    if (blockIdx.x >= BINB) {
        // cvt part: one float4 per thread over N*T/4 (exactly CVTB*1024 elements)
        int i = (blockIdx.x - BINB) * 1024 + tid;
        float4 v = x[i];
        f16x4 o;
        o.x = (f16)v.x; o.y = (f16)v.y; o.z = (f16)v.z; o.w = (f16)v.w;
        x16[i] = o;
        return;
    }

    if (tid < NBUCK) hist[tid] = 0;
    __syncthreads();
    int base = blockIdx.x * EPB;
    unsigned int val[4];
    short bkt[4];
    short rank[4];
#pragma unroll
    for (int k = 0; k < 4; k++) {
        int e = base + k * 1024 + tid;
        bkt[k] = -1;
        if (e < EE) {
            int s = ei[e];            // src
            int d = ei[EE + e];       // dst
            bkt[k] = (short)(d >> BSH);
            val[k] = ((unsigned int)(d & BMASK) << 20) | (unsigned int)s;
            rank[k] = (short)atomicAdd(&hist[bkt[k]], 1);
        }
    }
    __syncthreads();
    if (tid < NBUCK) gbase[tid] = hist[tid] ? atomicAdd(&gcursor[tid], hist[tid]) : 0;
    __syncthreads();
#pragma unroll
    for (int k = 0; k < 4; k++) {
        if (bkt[k] >= 0)
            binned[(size_t)bkt[k] * BCAP + gbase[bkt[k]] + (int)rank[k]] = val[k];
    }
}

// ---------- per-bucket (512 nodes): bucket-base scan + hist + scan + offsets/inv_cnt + place ----------
__global__ __launch_bounds__(1024)
void bucket_csr_kernel(const unsigned int* __restrict__ binned,
                       const int* __restrict__ gcursor,
                       int* __restrict__ offsets,
                       float* __restrict__ inv_cnt,
                       int* __restrict__ col) {
    __shared__ int hist[512];
    __shared__ int cur[512];
    __shared__ int smB[256];
    __shared__ int sc[512];
    int b = blockIdx.x;
    int tid = threadIdx.x;

    // bucket-base scan over all 196 bucket counts (threads 0..255; ~µs)
    if (tid < 256) smB[tid] = (tid < NBUCK) ? gcursor[tid] : 0;
    __syncthreads();
    for (int off = 1; off < 256; off <<= 1) {
        int v = 0;
        if (tid < 256 && tid >= off) v = smB[tid - off];
        __syncthreads();
        if (tid < 256) smB[tid] += v;
        __syncthreads();
    }
    int bucket_base = (b == 0) ? 0 : smB[b - 1];
    if (b == 0 && tid == 0) offsets[NN] = EE;

    int cnt = gcursor[b];
    const unsigned int* ePtr = binned + (size_t)b * BCAP;
    if (tid < 512) hist[tid] = 0;
    __syncthreads();
    for (int j = tid; j < cnt; j += 1024)          // ~8 iterations
        atomicAdd(&hist[ePtr[j] >> 20], 1);
    __syncthreads();
    int d = (tid < 512) ? hist[tid] : 0;
    if (tid < 512) sc[tid] = d;
    __syncthreads();
    for (int off = 1; off < 512; off <<= 1) {      // inclusive scan of 512 degrees
        int v = 0;
        if (tid < 512 && tid >= off) v = sc[tid - off];
        __syncthreads();
        if (tid < 512) sc[tid] += v;
        __syncthreads();
    }
    if (tid < 512) {
        int node = (b << BSH) + tid;
        int pos = bucket_base + sc[tid] - d;       // exclusive prefix
        if (node < NN) {
            offsets[node] = pos;
            inv_cnt[node] = 1.0f / (1.0f + (float)d);
            cur[tid] = pos;
        }
    }
    __syncthreads();
    // place: all writes land in this bucket's contiguous col window (~32 KB, L2-resident)
    for (int j = tid; j < cnt; j += 1024) {        // ~8 iterations
        unsigned int v = ePtr[j];
        int pos = atomicAdd(&cur[v >> 20], 1);
        col[pos] = (int)(v & 0xFFFFF);
    }
}

// ---------- layer: one wave per node gather (f16 sums incl. self), then block-wide
// LDS epilogue: conv K=9 + mean + bias + relu for the block's 4 nodes on all 256
// threads (2 t-values each) -- removes the 4x-redundant per-quarter-group epilogue.
__global__ __launch_bounds__(256)
void fused_layer_kernel(const f16x8* __restrict__ xin,
                        const int* __restrict__ offsets,
                        const int* __restrict__ col,
                        const float* __restrict__ inv_cnt,
                        const float* __restrict__ w9,
                        const float* __restrict__ bptr,
                        f16x8* __restrict__ yout) {
    // [8 zero halo | 128 sums | 8 zero halo] per node; row = 288 B (16B aligned)
    __shared__ __align__(16) f16 sb[4][144];
    int tid = threadIdx.x;
    int lane = tid & 63;
    int q = lane >> 4;
    int p = lane & 15;
    int w = tid >> 6;
    int node = __builtin_amdgcn_readfirstlane(blockIdx.x * 4 + w);

    float wr[KK];
#pragma unroll
    for (int k = 0; k < KK; k++) wr[k] = w9[k];
    float bb = bptr[0];

    // zero conv halos: dwords 0..3 and 68..71 of each row (disjoint from sum dwords 4..67)
    if (tid < 32) {
        int n = tid >> 3, k = tid & 7;
        ((int*)&sb[n][0])[(k < 4) ? k : (64 + k)] = 0;
    }

    // ---- gather: p = lane&15 owns t = {8p..8p+7}; quarter-groups q process 4 edges
    // per 1 KiB load; packed-fp16 accumulate; self row folded into q==0's acc ----
    int lo = offsets[node], hi = offsets[node + 1];
    int cnt = hi - lo;
    int my_col = (lane < cnt) ? col[lo + lane] : 0;
    int jn = cnt < 64 ? cnt : 64;

    const f16 z = (f16)0;
    f16x8 acc0 = {z, z, z, z, z, z, z, z};
    f16x8 acc1 = {z, z, z, z, z, z, z, z};
    if (q == 0) acc0 = xin[(node << 4) | p];       // self-loop row (f16 accumulate)

    int j = 0;
    for (; j + 7 < jn; j += 8) {               // 8 edges / iter, 2 loads in flight
        int c0 = __shfl(my_col, j + q);
        int c1 = __shfl(my_col, j + 4 + q);
        f16x8 v0 = xin[(c0 << 4) | p];
        f16x8 v1 = xin[(c1 << 4) | p];
        acc0 += v0;
        acc1 += v1;
    }
    for (; j + 3 < jn; j += 4) {               // 4 edges
        int c = __shfl(my_col, j + q);
        acc0 += xin[(c << 4) | p];
    }
    if (j < jn) {                              // tail 1..3 edges
        int rem = jn - j;
        int c = __shfl(my_col, j + (q < rem ? q : 0));
        f16x8 v = xin[(c << 4) | p];
        if (q < rem) acc1 += v;
    }
    for (int k = 64; k < cnt; k++) {           // degree > 64 (effectively never)
        int c = col[lo + k];
        f16x8 v = xin[(c << 4) | p];
        if (q == 0) acc0 += v;
    }
    acc0 += acc1;

    {   // combine the 4 quarter-groups: xor-16 then xor-32
        HU8 u; u.h = acc0;
        int4 o;
        o.x = __shfl_xor(u.i.x, 16); o.y = __shfl_xor(u.i.y, 16);
        o.z = __shfl_xor(u.i.z, 16); o.w = __shfl_xor(u.i.w, 16);
        HU8 w2; w2.i = o;
        acc0 += w2.h;
        u.h = acc0;
        o.x = __shfl_xor(u.i.x, 32); o.y = __shfl_xor(u.i.y, 32);
        o.z = __shfl_xor(u.i.z, 32); o.w = __shfl_xor(u.i.w, 32);
        w2.i = o;
        acc0 += w2.h;
    }

    if (q == 0) *(f16x8*)&sb[w][8 + p * 8] = acc0;   // 16B-aligned, 2-way banks (free)
    __syncthreads();

    // ---- epilogue: 4 nodes x 128 t = 512 outputs over 256 threads (2 t's each) ----
    // thread: n = tid>>6 (== its wave's node slot), t0 = 2*(tid&63)
    int t0 = (tid & 63) * 2;
    float A[10];
    const f16x2* sp = (const f16x2*)&sb[w][4 + t0];  // 4B-aligned, stride-1 dwords per wave
#pragma unroll
    for (int i = 0; i < 5; i++) {
        f16x2 v = sp[i];
        A[2 * i]     = (float)v.x;
        A[2 * i + 1] = (float)v.y;
    }
    float ic = inv_cnt[node];
    float r0 = 0.0f, r1 = 0.0f;
#pragma unroll
    for (int k = 0; k < KK; k++) {
        r0 += wr[k] * A[k];
        r1 += wr[k] * A[k + 1];
    }
    r0 = fmaxf(r0 * ic + bb, 0.0f);
    r1 = fmaxf(r1 * ic + bb, 0.0f);
    f16x2 o;
    o.x = (f16)r0;
    o.y = (f16)r1;
    ((f16x2*)yout)[node * 64 + (t0 >> 1)] = o;       // coalesced 4B stores, 256B/wave
}

// out[t,c] = b[c] + sum_n y3flat[t*NN + n] * Wout[c*NN + n]   (flat reinterpret view)
// (TT x NSPLIT) grid = 2048 blocks; Wout (1.2 MB) stays L2-resident; no LDS staging.
__global__ void out_kernel(const f16* __restrict__ y3, const float* __restrict__ Wout,
                           const float* __restrict__ bout, float* __restrict__ out) {
    int t = blockIdx.x;
    int sp = blockIdx.y;
    int tid = threadIdx.x;
    const int per = NN / NSPLIT;   // 6250
    int lo = sp * per;
    int hi = lo + per;
    float a0 = 0.0f, a1 = 0.0f, a2 = 0.0f;
    for (int n = lo + tid * 2; n < hi; n += 512) {
        f16x2 v2 = *(const f16x2*)(y3 + (size_t)t * NN + n);
        float vx = (float)v2.x, vy = (float)v2.y;
        float2 wA = *(const float2*)(Wout + n);
        float2 wB = *(const float2*)(Wout + NN + n);
        float2 wC = *(const float2*)(Wout + 2 * NN + n);
        a0 += vx * wA.x + vy * wA.y;
        a1 += vx * wB.x + vy * wB.y;
        a2 += vx * wC.x + vy * wC.y;
    }
    for (int o = 32; o > 0; o >>= 1) {
        a0 += __shfl_down(a0, o);
        a1 += __shfl_down(a1, o);
        a2 += __shfl_down(a2, o);
    }
    __shared__ float red[4][3];
    int wave = tid >> 6;
    if ((tid & 63) == 0) {
        red[wave][0] = a0;
        red[wave][1] = a1;
        red[wave][2] = a2;
    }
    __syncthreads();
    if (tid == 0) {
        float r0 = red[0][0] + red[1][0] + red[2][0] + red[3][0];
        float r1 = red[0][1] + red[1][1] + red[2][1] + red[3][1];
        float r2 = red[0][2] + red[1][2] + red[2][2] + red[3][2];
        if (sp == 0) {
            r0 += bout[0];
            r1 += bout[1];
            r2 += bout[2];
        }
        atomicAdd(&out[t * 3 + 0], r0);
        atomicAdd(&out[t * 3 + 1], r1);
        atomicAdd(&out[t * 3 + 2], r2);
    }
}

extern "C" void kernel_launch(void* const* d_in, const int* in_sizes, int n_in,
                              void* d_out, int out_size, void* d_ws, size_t ws_size,
                              hipStream_t stream) {
    const float4* x    = (const float4*)d_in[0];  // [N,T]
    const int*    ei   = (const int*)d_in[1];     // [2,E]
    const float*  cw   = (const float*)d_in[2];   // [L,1,1,K]
    const float*  cb   = (const float*)d_in[3];   // [L,1]
    const float*  Wout = (const float*)d_in[4];   // [3,N]
    const float*  bout = (const float*)d_in[5];   // [3]
    float* out = (float*)d_out;                   // [T,3]

    char* ws = (char*)d_ws;
    size_t off = 0;
    auto alloc = [&](size_t bytes) -> void* {
        void* p = ws + off;
        off += (bytes + 255) & ~(size_t)255;
        return p;
    };
    f16x8*        x16     = (f16x8*)alloc((size_t)NN * TT * 2);
    f16x8*        yA      = (f16x8*)alloc((size_t)NN * TT * 2);
    f16x8*        yB      = (f16x8*)alloc((size_t)NN * TT * 2);
    unsigned int* binned  = (unsigned int*)alloc((size_t)NBUCK * BCAP * 4);
    int*          gcursor = (int*)alloc((size_t)NBUCK * 4);
    int*          offsets = (int*)alloc((size_t)(NN + 1) * 4);
    float*        inv_cnt = (float*)alloc((size_t)NN * 4);
    int*          col     = (int*)alloc((size_t)EE * 4);

    // CSR build + cvt + out-zero (ws/out are re-poisoned before every call)
    hipMemsetAsync(gcursor, 0, (size_t)NBUCK * 4, stream);
    bin_cvt_kernel<<<BINB + CVTB + 1, 1024, 0, stream>>>(ei, gcursor, binned,
                                                         x, (f16x4*)x16, out);
    bucket_csr_kernel<<<NBUCK, 1024, 0, stream>>>(binned, gcursor, offsets, inv_cnt, col);

    // 3 fused layers (conv commuted past gather; bias/mean folded exactly)
    fused_layer_kernel<<<NN / 4, 256, 0, stream>>>(x16, offsets, col, inv_cnt,
                                                   cw + 0 * KK, cb + 0, yA);
    fused_layer_kernel<<<NN / 4, 256, 0, stream>>>(yA, offsets, col, inv_cnt,
                                                   cw + 1 * KK, cb + 1, yB);
    fused_layer_kernel<<<NN / 4, 256, 0, stream>>>(yB, offsets, col, inv_cnt,
                                                   cw + 2 * KK, cb + 2, yA);

    // output head (y3 = yA already has relu/mean applied; out pre-zeroed by bin_cvt)
    out_kernel<<<dim3(TT, NSPLIT), 256, 0, stream>>>((const f16*)yA, Wout, bout, out);
}

// Round 2
// 318.669 us; speedup vs baseline: 1.0436x; 1.0247x over previous
//
#include <hip/hip_runtime.h>

// Problem constants (match reference)
#define NN 100000
#define TT 128
#define EE 1600000
#define KK 9
#define NSPLIT 16                 // n-splits for output matmul
#define ZROW NN                   // dedicated all-zero row for padded gather lanes

// Binned CSR build: 512-node buckets
#define BSH 9
#define BMASK 511
#define NBUCK 196                 // ceil(100000/512)
#define BCAP 10240                // avg 8163/bucket, sigma~90 -> 23 sigma headroom
#define EPB 4096                  // edges per bin block
#define BINB 391                  // ceil(EE/EPB)
#define CVTB 3125                 // NN*TT/4 / 1024

typedef _Float16 f16;
typedef __attribute__((ext_vector_type(2))) _Float16 f16x2;
typedef __attribute__((ext_vector_type(4))) _Float16 f16x4;
typedef __attribute__((ext_vector_type(8))) _Float16 f16x8;

union HU8 { f16x8 h; int4 i; };

// ---------- fused: bin edges (blocks 0..BINB) + x fp32->fp16 + zero out ----------
// Packed edge: (dlocal << 20) | src   (src < 2^17, dlocal < 2^9)
__global__ __launch_bounds__(1024)
void bin_cvt_kernel(const int* __restrict__ ei, int* __restrict__ gcursor,
                    unsigned int* __restrict__ binned,
                    const float4* __restrict__ x, f16x4* __restrict__ x16,
                    float* __restrict__ out,
                    int* __restrict__ zx, int* __restrict__ zyA, int* __restrict__ zyB) {
    __shared__ int hist[NBUCK];
    __shared__ int gbase[NBUCK];
    int tid = threadIdx.x;

    if (blockIdx.x >= BINB + CVTB) {          // one block: zero out accumulator + zero-rows
        if (tid < TT * 3) out[tid] = 0.0f;
        int k = tid - 512;                    // zero row NN of x16/yA/yB (64 dwords each)
        if (k >= 0 && k < 64)        zx[k]        = 0;
        else if (k >= 64 && k < 128) zyA[k - 64]  = 0;
        else if (k >= 128 && k < 192) zyB[k - 128] = 0;
        return;
    }
    if (blockIdx.x >= BINB) {
        // cvt part: one float4 per thread over N*T/4 (exactly CVTB*1024 elements)
        int i = (blockIdx.x - BINB) * 1024 + tid;
        float4 v = x[i];
        f16x4 o;
        o.x = (f16)v.x; o.y = (f16)v.y; o.z = (f16)v.z; o.w = (f16)v.w;
        x16[i] = o;
        return;
    }

    if (tid < NBUCK) hist[tid] = 0;
    __syncthreads();
    int base = blockIdx.x * EPB;
    unsigned int val[4];
    short bkt[4];
    short rank[4];
#pragma unroll
    for (int k = 0; k < 4; k++) {
        int e = base + k * 1024 + tid;
        bkt[k] = -1;
        if (e < EE) {
            int s = ei[e];            // src
            int d = ei[EE + e];       // dst
            bkt[k] = (short)(d >> BSH);
            val[k] = ((unsigned int)(d & BMASK) << 20) | (unsigned int)s;
            rank[k] = (short)atomicAdd(&hist[bkt[k]], 1);
        }
    }
    __syncthreads();
    if (tid < NBUCK) gbase[tid] = hist[tid] ? atomicAdd(&gcursor[tid], hist[tid]) : 0;
    __syncthreads();
#pragma unroll
    for (int k = 0; k < 4; k++) {
        if (bkt[k] >= 0)
            binned[(size_t)bkt[k] * BCAP + gbase[bkt[k]] + (int)rank[k]] = val[k];
    }
}

// ---------- per-bucket (512 nodes): bucket-base scan + hist + scan + offsets/inv_cnt + place ----------
__global__ __launch_bounds__(1024)
void bucket_csr_kernel(const unsigned int* __restrict__ binned,
                       const int* __restrict__ gcursor,
                       int* __restrict__ offsets,
                       float* __restrict__ inv_cnt,
                       int* __restrict__ col) {
    __shared__ int hist[512];
    __shared__ int cur[512];
    __shared__ int smB[256];
    __shared__ int sc[512];
    int b = blockIdx.x;
    int tid = threadIdx.x;

    // bucket-base scan over all 196 bucket counts (threads 0..255; ~µs)
    if (tid < 256) smB[tid] = (tid < NBUCK) ? gcursor[tid] : 0;
    __syncthreads();
    for (int off = 1; off < 256; off <<= 1) {
        int v = 0;
        if (tid < 256 && tid >= off) v = smB[tid - off];
        __syncthreads();
        if (tid < 256) smB[tid] += v;
        __syncthreads();
    }
    int bucket_base = (b == 0) ? 0 : smB[b - 1];
    if (b == 0 && tid == 0) offsets[NN] = EE;

    int cnt = gcursor[b];
    const unsigned int* ePtr = binned + (size_t)b * BCAP;
    if (tid < 512) hist[tid] = 0;
    __syncthreads();
    for (int j = tid; j < cnt; j += 1024)          // ~8 iterations
        atomicAdd(&hist[ePtr[j] >> 20], 1);
    __syncthreads();
    int d = (tid < 512) ? hist[tid] : 0;
    if (tid < 512) sc[tid] = d;
    __syncthreads();
    for (int off = 1; off < 512; off <<= 1) {      // inclusive scan of 512 degrees
        int v = 0;
        if (tid < 512 && tid >= off) v = sc[tid - off];
        __syncthreads();
        if (tid < 512) sc[tid] += v;
        __syncthreads();
    }
    if (tid < 512) {
        int node = (b << BSH) + tid;
        int pos = bucket_base + sc[tid] - d;       // exclusive prefix
        if (node < NN) {
            offsets[node] = pos;
            inv_cnt[node] = 1.0f / (1.0f + (float)d);
            cur[tid] = pos;
        }
    }
    __syncthreads();
    // place: all writes land in this bucket's contiguous col window (~32 KB, L2-resident)
    for (int j = tid; j < cnt; j += 1024) {        // ~8 iterations
        unsigned int v = ePtr[j];
        int pos = atomicAdd(&cur[v >> 20], 1);
        col[pos] = (int)(v & 0xFFFFF);
    }
}

// ---------- layer: one wave per node gather (f16 sums incl. self), then block-wide
// LDS epilogue. Gather issues 8 independent 16B loads (32 edges) back-to-back for
// deep MLP; out-of-range lanes gather the L1-hot zero row (ZROW) -> no tail code.
__global__ __launch_bounds__(256)
void fused_layer_kernel(const f16x8* __restrict__ xin,
                        const int* __restrict__ offsets,
                        const int* __restrict__ col,
                        const float* __restrict__ inv_cnt,
                        const float* __restrict__ w9,
                        const float* __restrict__ bptr,
                        f16x8* __restrict__ yout) {
    // [8 zero halo | 128 sums | 8 zero halo] per node; row = 288 B (16B aligned)
    __shared__ __align__(16) f16 sb[4][144];
    int tid = threadIdx.x;
    int lane = tid & 63;
    int q = lane >> 4;
    int p = lane & 15;
    int w = tid >> 6;
    int node = __builtin_amdgcn_readfirstlane(blockIdx.x * 4 + w);

    float wr[KK];
#pragma unroll
    for (int k = 0; k < KK; k++) wr[k] = w9[k];
    float bb = bptr[0];

    // zero conv halos: dwords 0..3 and 68..71 of each row (disjoint from sum dwords 4..67)
    if (tid < 32) {
        int n = tid >> 3, k = tid & 7;
        ((int*)&sb[n][0])[(k < 4) ? k : (64 + k)] = 0;
    }

    // ---- gather: p = lane&15 owns t = {8p..8p+7}; quarter-groups q process 4 edges
    // per 1 KiB load; packed-fp16 accumulate; self row folded into q==0's acc ----
    int lo = offsets[node], hi = offsets[node + 1];
    int cnt = hi - lo;
    int my_col = (lane < cnt) ? col[lo + lane] : ZROW;   // pad lanes -> zero row
    int jn = cnt < 64 ? cnt : 64;

    const f16 z = (f16)0;
    f16x8 acc0 = {z, z, z, z, z, z, z, z};
    f16x8 acc1 = {z, z, z, z, z, z, z, z};
    if (q == 0) acc0 = xin[(node << 4) | p];       // self-loop row (f16 accumulate)

    for (int j = 0; j < jn; j += 32) {             // 32 edges: 8 indep loads in flight
        int c0 = __shfl(my_col, j + q);
        int c1 = __shfl(my_col, j + 4 + q);
        int c2 = __shfl(my_col, j + 8 + q);
        int c3 = __shfl(my_col, j + 12 + q);
        int c4 = __shfl(my_col, j + 16 + q);
        int c5 = __shfl(my_col, j + 20 + q);
        int c6 = __shfl(my_col, j + 24 + q);
        int c7 = __shfl(my_col, j + 28 + q);
        f16x8 u0 = xin[(c0 << 4) | p];
        f16x8 u1 = xin[(c1 << 4) | p];
        f16x8 u2 = xin[(c2 << 4) | p];
        f16x8 u3 = xin[(c3 << 4) | p];
        f16x8 u4 = xin[(c4 << 4) | p];
        f16x8 u5 = xin[(c5 << 4) | p];
        f16x8 u6 = xin[(c6 << 4) | p];
        f16x8 u7 = xin[(c7 << 4) | p];
        acc0 += u0; acc1 += u1;
        acc0 += u2; acc1 += u3;
        acc0 += u4; acc1 += u5;
        acc0 += u6; acc1 += u7;
    }
    for (int k = 64; k < cnt; k++) {           // degree > 64 (effectively never)
        int c = col[lo + k];
        f16x8 v = xin[(c << 4) | p];
        if (q == 0) acc0 += v;
    }
    acc0 += acc1;

    {   // combine the 4 quarter-groups: xor-16 then xor-32
        HU8 u; u.h = acc0;
        int4 o;
        o.x = __shfl_xor(u.i.x, 16); o.y = __shfl_xor(u.i.y, 16);
        o.z = __shfl_xor(u.i.z, 16); o.w = __shfl_xor(u.i.w, 16);
        HU8 w2; w2.i = o;
        acc0 += w2.h;
        u.h = acc0;
        o.x = __shfl_xor(u.i.x, 32); o.y = __shfl_xor(u.i.y, 32);
        o.z = __shfl_xor(u.i.z, 32); o.w = __shfl_xor(u.i.w, 32);
        w2.i = o;
        acc0 += w2.h;
    }

    if (q == 0) *(f16x8*)&sb[w][8 + p * 8] = acc0;   // 16B-aligned, 2-way banks (free)
    __syncthreads();

    // ---- epilogue: 4 nodes x 128 t = 512 outputs over 256 threads (2 t's each) ----
    // thread: n = tid>>6 (== its wave's node slot), t0 = 2*(tid&63)
    int t0 = (tid & 63) * 2;
    float A[10];
    const f16x2* sp = (const f16x2*)&sb[w][4 + t0];  // 4B-aligned, stride-1 dwords per wave
#pragma unroll
    for (int i = 0; i < 5; i++) {
        f16x2 v = sp[i];
        A[2 * i]     = (float)v.x;
        A[2 * i + 1] = (float)v.y;
    }
    float ic = inv_cnt[node];
    float r0 = 0.0f, r1 = 0.0f;
#pragma unroll
    for (int k = 0; k < KK; k++) {
        r0 += wr[k] * A[k];
        r1 += wr[k] * A[k + 1];
    }
    r0 = fmaxf(r0 * ic + bb, 0.0f);
    r1 = fmaxf(r1 * ic + bb, 0.0f);
    f16x2 o;
    o.x = (f16)r0;
    o.y = (f16)r1;
    ((f16x2*)yout)[node * 64 + (t0 >> 1)] = o;       // coalesced 4B stores, 256B/wave
}

// out[t,c] = b[c] + sum_n y3flat[t*NN + n] * Wout[c*NN + n]   (flat reinterpret view)
// (TT x NSPLIT) grid = 2048 blocks; Wout (1.2 MB) stays L2-resident; no LDS staging.
__global__ void out_kernel(const f16* __restrict__ y3, const float* __restrict__ Wout,
                           const float* __restrict__ bout, float* __restrict__ out) {
    int t = blockIdx.x;
    int sp = blockIdx.y;
    int tid = threadIdx.x;
    const int per = NN / NSPLIT;   // 6250
    int lo = sp * per;
    int hi = lo + per;
    float a0 = 0.0f, a1 = 0.0f, a2 = 0.0f;
    for (int n = lo + tid * 2; n < hi; n += 512) {
        f16x2 v2 = *(const f16x2*)(y3 + (size_t)t * NN + n);
        float vx = (float)v2.x, vy = (float)v2.y;
        float2 wA = *(const float2*)(Wout + n);
        float2 wB = *(const float2*)(Wout + NN + n);
        float2 wC = *(const float2*)(Wout + 2 * NN + n);
        a0 += vx * wA.x + vy * wA.y;
        a1 += vx * wB.x + vy * wB.y;
        a2 += vx * wC.x + vy * wC.y;
    }
    for (int o = 32; o > 0; o >>= 1) {
        a0 += __shfl_down(a0, o);
        a1 += __shfl_down(a1, o);
        a2 += __shfl_down(a2, o);
    }
    __shared__ float red[4][3];
    int wave = tid >> 6;
    if ((tid & 63) == 0) {
        red[wave][0] = a0;
        red[wave][1] = a1;
        red[wave][2] = a2;
    }
    __syncthreads();
    if (tid == 0) {
        float r0 = red[0][0] + red[1][0] + red[2][0] + red[3][0];
        float r1 = red[0][1] + red[1][1] + red[2][1] + red[3][1];
        float r2 = red[0][2] + red[1][2] + red[2][2] + red[3][2];
        if (sp == 0) {
            r0 += bout[0];
            r1 += bout[1];
            r2 += bout[2];
        }
        atomicAdd(&out[t * 3 + 0], r0);
        atomicAdd(&out[t * 3 + 1], r1);
        atomicAdd(&out[t * 3 + 2], r2);
    }
}

extern "C" void kernel_launch(void* const* d_in, const int* in_sizes, int n_in,
                              void* d_out, int out_size, void* d_ws, size_t ws_size,
                              hipStream_t stream) {
    const float4* x    = (const float4*)d_in[0];  // [N,T]
    const int*    ei   = (const int*)d_in[1];     // [2,E]
    const float*  cw   = (const float*)d_in[2];   // [L,1,1,K]
    const float*  cb   = (const float*)d_in[3];   // [L,1]
    const float*  Wout = (const float*)d_in[4];   // [3,N]
    const float*  bout = (const float*)d_in[5];   // [3]
    float* out = (float*)d_out;                   // [T,3]

    char* ws = (char*)d_ws;
    size_t off = 0;
    auto alloc = [&](size_t bytes) -> void* {
        void* p = ws + off;
        off += (bytes + 255) & ~(size_t)255;
        return p;
    };
    // NN+1 rows: row NN is the shared all-zero row for padded gather lanes
    f16x8*        x16     = (f16x8*)alloc((size_t)(NN + 1) * TT * 2);
    f16x8*        yA      = (f16x8*)alloc((size_t)(NN + 1) * TT * 2);
    f16x8*        yB      = (f16x8*)alloc((size_t)(NN + 1) * TT * 2);
    unsigned int* binned  = (unsigned int*)alloc((size_t)NBUCK * BCAP * 4);
    int*          gcursor = (int*)alloc((size_t)NBUCK * 4);
    int*          offsets = (int*)alloc((size_t)(NN + 1) * 4);
    float*        inv_cnt = (float*)alloc((size_t)NN * 4);
    int*          col     = (int*)alloc((size_t)EE * 4);

    // CSR build + cvt + out-zero + zero-row init (ws/out are re-poisoned every call)
    hipMemsetAsync(gcursor, 0, (size_t)NBUCK * 4, stream);
    bin_cvt_kernel<<<BINB + CVTB + 1, 1024, 0, stream>>>(
        ei, gcursor, binned, x, (f16x4*)x16, out,
        (int*)(x16 + (size_t)NN * 16), (int*)(yA + (size_t)NN * 16),
        (int*)(yB + (size_t)NN * 16));
    bucket_csr_kernel<<<NBUCK, 1024, 0, stream>>>(binned, gcursor, offsets, inv_cnt, col);

    // 3 fused layers (conv commuted past gather; bias/mean folded exactly)
    fused_layer_kernel<<<NN / 4, 256, 0, stream>>>(x16, offsets, col, inv_cnt,
                                                   cw + 0 * KK, cb + 0, yA);
    fused_layer_kernel<<<NN / 4, 256, 0, stream>>>(yA, offsets, col, inv_cnt,
                                                   cw + 1 * KK, cb + 1, yB);
    fused_layer_kernel<<<NN / 4, 256, 0, stream>>>(yB, offsets, col, inv_cnt,
                                                   cw + 2 * KK, cb + 2, yA);

    // output head (y3 = yA already has relu/mean applied; out pre-zeroed by bin_cvt)
    out_kernel<<<dim3(TT, NSPLIT), 256, 0, stream>>>((const f16*)yA, Wout, bout, out);
}